// Round 2
// baseline (1100.123 us; speedup 1.0000x reference)
//
#include <hip/hip_runtime.h>

#define Bdim 2
#define Tdim 2048
#define Cdim 2048
#define Hn 16
#define Dh 128
#define NKB 16   // Cdim/128 k-blocks per row

typedef float f32x4 __attribute__((ext_vector_type(4)));
typedef short s16x8 __attribute__((ext_vector_type(8)));

// ---------- numerics helpers ----------

// fp32 -> float8_e5m2 (RNE, subnormals, inf past 61440) -> fp32. Matches ml_dtypes.
__device__ __forceinline__ float q8_e5m2(float x) {
    unsigned int u = __float_as_uint(x);
    unsigned int sign = u & 0x80000000u;
    float ax = __uint_as_float(u & 0x7fffffffu);
    float r;
    if (ax < 6.103515625e-05f) {              // subnormal range: grid 2^-16
        r = rintf(ax * 65536.0f) * (1.0f / 65536.0f);
    } else if (ax >= 61440.0f) {
        r = __uint_as_float(0x7f800000u);
    } else {
        unsigned int m = __float_as_uint(ax);
        unsigned int rem  = m & 0x001FFFFFu;
        unsigned int keep = m & 0xFFE00000u;
        unsigned int lsb  = (m >> 21) & 1u;
        if (rem > 0x00100000u || (rem == 0x00100000u && lsb)) keep += 0x00200000u;
        r = __uint_as_float(keep);
    }
    return __uint_as_float(__float_as_uint(r) | sign);
}

__device__ __forceinline__ unsigned short f2bf(float f) {
    unsigned int u = __float_as_uint(f);
    u += 0x7fffu + ((u >> 16) & 1u);
    return (unsigned short)(u >> 16);
}
__device__ __forceinline__ float bf2f(unsigned short h) {
    return __uint_as_float((unsigned int)h << 16);
}

// ---------- act quant: per-128 block. out = bf16(q8(x/s)) [EXACT] + scale ----------
__global__ __launch_bounds__(256) void act_quant_q8_k(const float* __restrict__ in,
                                                      unsigned short* __restrict__ q,
                                                      float* __restrict__ S, int n128) {
    int wid = (int)((blockIdx.x * 256u + threadIdx.x) >> 6);
    int lane = threadIdx.x & 63;
    if (wid >= n128) return;
    const float* p = in + (size_t)wid * 128;
    float a = p[lane], b = p[lane + 64];
    float m = fmaxf(fabsf(a), fabsf(b));
#pragma unroll
    for (int o = 32; o; o >>= 1) m = fmaxf(m, __shfl_xor(m, o));
    float s = fmaxf(m / 57344.0f, 1e-12f);
    unsigned short* qp = q + (size_t)wid * 128;
    qp[lane]      = f2bf(q8_e5m2(a / s));
    qp[lane + 64] = f2bf(q8_e5m2(b / s));
    if (lane == 0) S[wid] = s;
}

// ---------- weight quant: out = bf16(q8(w)) [EXACT, scale applied in GEMM epilogue] ----------
__global__ __launch_bounds__(256) void w_quant_k(const float* __restrict__ w,
                                                 unsigned short* __restrict__ out, int n) {
    int i = (blockIdx.x * 256 + threadIdx.x) * 4;
    if (i >= n) return;
    float4 t = *(const float4*)(w + i);
    out[i + 0] = f2bf(q8_e5m2(t.x));
    out[i + 1] = f2bf(q8_e5m2(t.y));
    out[i + 2] = f2bf(q8_e5m2(t.z));
    out[i + 3] = f2bf(q8_e5m2(t.w));
}

// ---------- GEMM: C[M,N] = (Aq * Sa_blockwise) @ Bq^T * Sb_col ----------
// Aq: exact-bf16 e5m2 activations, Sa: per (row, k/128) scales.
// Bq: exact-bf16 e5m2 weights, Sb: per (col/128) scales.
// OUTF32=0: emit hi/lo bf16 planes. OUTF32=1: emit fp32.
#define LDST 40

template<int OUTF32>
__global__ __launch_bounds__(256) void gemm_k(const unsigned short* __restrict__ Aq,
                                              const float* __restrict__ Sa,
                                              const unsigned short* __restrict__ Bq,
                                              const float* __restrict__ Sb,
                                              unsigned short* __restrict__ Oh,
                                              unsigned short* __restrict__ Ol,
                                              float* __restrict__ Of,
                                              int M, int N, int K) {
    __shared__ unsigned short As[128 * LDST];
    __shared__ unsigned short Bs[128 * LDST];
    int tid = threadIdx.x;
    int lane = tid & 63, wid = tid >> 6;
    int wr = wid >> 1, wc = wid & 1;
    int bm = blockIdx.y * 128, bn = blockIdx.x * 128;

    f32x4 acc[4][4], accp[4][4];
#pragma unroll
    for (int i = 0; i < 4; ++i)
#pragma unroll
        for (int j = 0; j < 4; ++j) {
            acc[i][j] = (f32x4){0.f, 0.f, 0.f, 0.f};
            accp[i][j] = (f32x4){0.f, 0.f, 0.f, 0.f};
        }

    int srow = tid >> 2;
    int scol = (tid & 3) * 8;
    const int frow = lane & 15;
    const int fk   = (lane >> 4) * 8;
    const int rbase = (lane >> 4) * 4;
    const int nkb = K >> 7;

    for (int kb = 0; kb < nkb; ++kb) {
#pragma unroll
        for (int ks = 0; ks < 4; ++ks) {
            int k0 = kb * 128 + ks * 32;
            __syncthreads();
#pragma unroll
            for (int hh = 0; hh < 2; ++hh) {
                int r = srow + hh * 64;
                *(int4*)(void*)(As + r * LDST + scol) =
                    *(const int4*)(const void*)(Aq + (size_t)(bm + r) * K + k0 + scol);
                *(int4*)(void*)(Bs + r * LDST + scol) =
                    *(const int4*)(const void*)(Bq + (size_t)(bn + r) * K + k0 + scol);
            }
            __syncthreads();
            s16x8 af[4], bfr[4];
#pragma unroll
            for (int m = 0; m < 4; ++m)
                af[m] = *(const s16x8*)(const void*)(As + (wr * 64 + m * 16 + frow) * LDST + fk);
#pragma unroll
            for (int n = 0; n < 4; ++n)
                bfr[n] = *(const s16x8*)(const void*)(Bs + (wc * 64 + n * 16 + frow) * LDST + fk);
#pragma unroll
            for (int m = 0; m < 4; ++m)
#pragma unroll
                for (int n = 0; n < 4; ++n)
                    accp[m][n] = __builtin_amdgcn_mfma_f32_16x16x32_bf16(af[m], bfr[n], accp[m][n], 0, 0, 0);
        }
        // fold partial block into acc with per-row activation scale
#pragma unroll
        for (int m = 0; m < 4; ++m) {
            int rowb = bm + wr * 64 + m * 16 + rbase;
            float s0 = Sa[(size_t)(rowb + 0) * nkb + kb];
            float s1 = Sa[(size_t)(rowb + 1) * nkb + kb];
            float s2 = Sa[(size_t)(rowb + 2) * nkb + kb];
            float s3 = Sa[(size_t)(rowb + 3) * nkb + kb];
#pragma unroll
            for (int n = 0; n < 4; ++n) {
                acc[m][n][0] += s0 * accp[m][n][0];
                acc[m][n][1] += s1 * accp[m][n][1];
                acc[m][n][2] += s2 * accp[m][n][2];
                acc[m][n][3] += s3 * accp[m][n][3];
                accp[m][n] = (f32x4){0.f, 0.f, 0.f, 0.f};
            }
        }
    }

    int row0 = bm + wr * 64, col0 = bn + wc * 64;
    int cl = lane & 15;
#pragma unroll
    for (int n = 0; n < 4; ++n) {
        float sb = Sb[(col0 + n * 16) >> 7];
#pragma unroll
        for (int m = 0; m < 4; ++m)
#pragma unroll
            for (int r = 0; r < 4; ++r) {
                int row = row0 + m * 16 + rbase + r;
                int col = col0 + n * 16 + cl;
                float val = acc[m][n][r] * sb;
                if (OUTF32) {
                    Of[(size_t)row * N + col] = val;
                } else {
                    unsigned short hi = f2bf(val);
                    Oh[(size_t)row * N + col] = hi;
                    Ol[(size_t)row * N + col] = f2bf(val - bf2f(hi));
                }
            }
    }
}

// ---------- flash attention, hi/lo split operands, fused ctx e5m2 quant ----------
#define QB 64
#define KB 32
#define KLD 136
#define VLD 40

__global__ __launch_bounds__(256) void attn_k(const unsigned short* __restrict__ Qh,
                                              const unsigned short* __restrict__ Ql,
                                              const unsigned short* __restrict__ Kbh,
                                              const unsigned short* __restrict__ Kbl,
                                              const unsigned short* __restrict__ Vbh,
                                              const unsigned short* __restrict__ Vbl,
                                              unsigned short* __restrict__ ctxq,
                                              float* __restrict__ Sc) {
    __shared__ unsigned short Ksh[KB * KLD], Ksl[KB * KLD];
    __shared__ unsigned short Vth[Dh * VLD], Vtl[Dh * VLD];
    __shared__ unsigned short Psh[4][16 * VLD], Psl[4][16 * VLD];

    int tid = threadIdx.x, lane = tid & 63, wid = tid >> 6;
    int qt = blockIdx.x, h = blockIdx.y, b = blockIdx.z;
    const size_t base = (size_t)b * Tdim * Cdim + (size_t)h * Dh;
    const unsigned short* Qhp = Qh + base;
    const unsigned short* Qlp = Ql + base;
    const unsigned short* Khp = Kbh + base;
    const unsigned short* Klp = Kbl + base;
    const unsigned short* Vhp = Vbh + base;
    const unsigned short* Vlp = Vbl + base;

    int q0 = qt * QB;
    int qrow_lo = q0 + wid * 16;
    int cl = lane & 15;
    int fk = (lane >> 4) * 8;
    int rbase = (lane >> 4) * 4;
    int myrow = qrow_lo + cl;

    s16x8 qfh[4], qfl[4];
#pragma unroll
    for (int c = 0; c < 4; ++c) {
        qfh[c] = *(const s16x8*)(const void*)(Qhp + (size_t)myrow * Cdim + c * 32 + fk);
        qfl[c] = *(const s16x8*)(const void*)(Qlp + (size_t)myrow * Cdim + c * 32 + fk);
    }

    f32x4 acc[8];
#pragma unroll
    for (int n = 0; n < 8; ++n) acc[n] = (f32x4){0.f, 0.f, 0.f, 0.f};
    float mrun[4], lrun[4];
#pragma unroll
    for (int r = 0; r < 4; ++r) { mrun[r] = -__builtin_inff(); lrun[r] = 0.f; }

    const float scale = 0.088388347648318447f;  // 1/sqrt(128)
    int ntile = (q0 + QB - 1) / KB + 1;
    int qmax_w = qrow_lo + 15;

    for (int t = 0; t < ntile; ++t) {
        int j0 = t * KB;
        __syncthreads();
        for (int c2 = tid; c2 < (KB * Dh / 8); c2 += 256) {
            int kr = c2 >> 4, kc = (c2 & 15) * 8;
            *(int4*)(void*)(Ksh + kr * KLD + kc) =
                *(const int4*)(const void*)(Khp + (size_t)(j0 + kr) * Cdim + kc);
            *(int4*)(void*)(Ksl + kr * KLD + kc) =
                *(const int4*)(const void*)(Klp + (size_t)(j0 + kr) * Cdim + kc);
            s16x8 tvh = *(const s16x8*)(const void*)(Vhp + (size_t)(j0 + kr) * Cdim + kc);
            s16x8 tvl = *(const s16x8*)(const void*)(Vlp + (size_t)(j0 + kr) * Cdim + kc);
#pragma unroll
            for (int i2 = 0; i2 < 8; ++i2) {
                Vth[(kc + i2) * VLD + kr] = (unsigned short)tvh[i2];
                Vtl[(kc + i2) * VLD + kr] = (unsigned short)tvl[i2];
            }
        }
        __syncthreads();
        if (j0 <= qmax_w) {
            f32x4 sf[2];
#pragma unroll
            for (int st = 0; st < 2; ++st) {
                f32x4 sa = (f32x4){0.f, 0.f, 0.f, 0.f};
#pragma unroll
                for (int c = 0; c < 4; ++c) {
                    s16x8 kfh = *(const s16x8*)(const void*)(Ksh + (st * 16 + cl) * KLD + c * 32 + fk);
                    s16x8 kfl = *(const s16x8*)(const void*)(Ksl + (st * 16 + cl) * KLD + c * 32 + fk);
                    sa = __builtin_amdgcn_mfma_f32_16x16x32_bf16(qfh[c], kfh, sa, 0, 0, 0);
                    sa = __builtin_amdgcn_mfma_f32_16x16x32_bf16(qfh[c], kfl, sa, 0, 0, 0);
                    sa = __builtin_amdgcn_mfma_f32_16x16x32_bf16(qfl[c], kfh, sa, 0, 0, 0);
                }
                sf[st] = sa;
            }
#pragma unroll
            for (int st = 0; st < 2; ++st) {
                int key = j0 + st * 16 + cl;
#pragma unroll
                for (int r = 0; r < 4; ++r) {
                    int qr = qrow_lo + rbase + r;
                    float sv = sf[st][r] * scale;
                    sf[st][r] = (key <= qr) ? sv : -__builtin_inff();
                }
            }
            float p0[4], p1[4], corr[4];
#pragma unroll
            for (int r = 0; r < 4; ++r) {
                float tm = fmaxf(sf[0][r], sf[1][r]);
#pragma unroll
                for (int o = 8; o; o >>= 1) tm = fmaxf(tm, __shfl_xor(tm, o));
                float mn = fmaxf(mrun[r], tm);
                corr[r] = expf(mrun[r] - mn);
                mrun[r] = mn;
                p0[r] = expf(sf[0][r] - mn);
                p1[r] = expf(sf[1][r] - mn);
                float rs = p0[r] + p1[r];
#pragma unroll
                for (int o = 8; o; o >>= 1) rs += __shfl_xor(rs, o);
                lrun[r] = lrun[r] * corr[r] + rs;
            }
#pragma unroll
            for (int n = 0; n < 8; ++n)
#pragma unroll
                for (int r = 0; r < 4; ++r) acc[n][r] *= corr[r];
            unsigned short* psh = &Psh[wid][0];
            unsigned short* psl = &Psl[wid][0];
#pragma unroll
            for (int r = 0; r < 4; ++r) {
                unsigned short h0 = f2bf(p0[r]);
                unsigned short h1 = f2bf(p1[r]);
                psh[(rbase + r) * VLD + cl]      = h0;
                psl[(rbase + r) * VLD + cl]      = f2bf(p0[r] - bf2f(h0));
                psh[(rbase + r) * VLD + 16 + cl] = h1;
                psl[(rbase + r) * VLD + 16 + cl] = f2bf(p1[r] - bf2f(h1));
            }
            s16x8 pfh = *(const s16x8*)(const void*)(psh + cl * VLD + fk);
            s16x8 pfl = *(const s16x8*)(const void*)(psl + cl * VLD + fk);
#pragma unroll
            for (int n = 0; n < 8; ++n) {
                s16x8 vfh = *(const s16x8*)(const void*)(Vth + (n * 16 + cl) * VLD + fk);
                s16x8 vfl = *(const s16x8*)(const void*)(Vtl + (n * 16 + cl) * VLD + fk);
                acc[n] = __builtin_amdgcn_mfma_f32_16x16x32_bf16(pfh, vfh, acc[n], 0, 0, 0);
                acc[n] = __builtin_amdgcn_mfma_f32_16x16x32_bf16(pfh, vfl, acc[n], 0, 0, 0);
                acc[n] = __builtin_amdgcn_mfma_f32_16x16x32_bf16(pfl, vfh, acc[n], 0, 0, 0);
            }
        }
    }
    // epilogue: normalize + fused e5m2 block quant (block == this head's 128 cols)
    unsigned short* cq = ctxq + base;
#pragma unroll
    for (int r = 0; r < 4; ++r) {
        int trow = qrow_lo + rbase + r;
        float inv = 1.0f / lrun[r];
        float vals[8];
        float am = 0.f;
#pragma unroll
        for (int n = 0; n < 8; ++n) {
            vals[n] = acc[n][r] * inv;
            am = fmaxf(am, fabsf(vals[n]));
        }
#pragma unroll
        for (int o = 8; o; o >>= 1) am = fmaxf(am, __shfl_xor(am, o));
        float s = fmaxf(am / 57344.0f, 1e-12f);
#pragma unroll
        for (int n = 0; n < 8; ++n)
            cq[(size_t)trow * Cdim + n * 16 + cl] = f2bf(q8_e5m2(vals[n] / s));
        if (cl == 0) Sc[((size_t)b * Tdim + trow) * NKB + h] = s;
    }
}

// ---------- launch ----------
extern "C" void kernel_launch(void* const* d_in, const int* in_sizes, int n_in,
                              void* d_out, int out_size, void* d_ws, size_t ws_size,
                              hipStream_t stream) {
    const float* x  = (const float*)d_in[0];
    const float* wq = (const float*)d_in[2];
    const float* wk = (const float*)d_in[3];
    const float* wv = (const float*)d_in[4];
    const float* wo = (const float*)d_in[5];
    const float* sq = (const float*)d_in[6];
    const float* sk = (const float*)d_in[7];
    const float* sv = (const float*)d_in[8];
    const float* so = (const float*)d_in[9];

    const size_t MB = 1ull << 20;
    char* ws = (char*)d_ws;
    unsigned short* xq  = (unsigned short*)(ws);             // 16MB exact-q8 activations
    float*          Sx  = (float*)(ws + 16 * MB);            // 256KB act scales
    unsigned short* wdq = (unsigned short*)(ws + 17 * MB);   // 8MB exact-q8 weight (reused)
    unsigned short* qh  = (unsigned short*)(ws + 25 * MB);
    unsigned short* ql  = (unsigned short*)(ws + 41 * MB);
    unsigned short* kh  = (unsigned short*)(ws + 57 * MB);
    unsigned short* kl  = (unsigned short*)(ws + 73 * MB);
    unsigned short* vh  = (unsigned short*)(ws + 89 * MB);
    unsigned short* vl  = (unsigned short*)(ws + 105 * MB);
    unsigned short* cq  = (unsigned short*)(ws + 121 * MB);  // 16MB exact-q8 ctx
    float*          Scx = (float*)(ws + 137 * MB);           // 256KB ctx scales

    const int n128 = Bdim * Tdim * Cdim / 128;  // 65536
    const int wn = Cdim * Cdim;
    const int Mr = Bdim * Tdim;

    act_quant_q8_k<<<n128 / 4, 256, 0, stream>>>(x, xq, Sx, n128);

    dim3 gg(Cdim / 128, Mr / 128);
    w_quant_k<<<wn / 1024, 256, 0, stream>>>(wq, wdq, wn);
    gemm_k<0><<<gg, 256, 0, stream>>>(xq, Sx, wdq, sq, qh, ql, nullptr, Mr, Cdim, Cdim);
    w_quant_k<<<wn / 1024, 256, 0, stream>>>(wk, wdq, wn);
    gemm_k<0><<<gg, 256, 0, stream>>>(xq, Sx, wdq, sk, kh, kl, nullptr, Mr, Cdim, Cdim);
    w_quant_k<<<wn / 1024, 256, 0, stream>>>(wv, wdq, wn);
    gemm_k<0><<<gg, 256, 0, stream>>>(xq, Sx, wdq, sv, vh, vl, nullptr, Mr, Cdim, Cdim);

    dim3 ag(Tdim / QB, Hn, Bdim);
    attn_k<<<ag, 256, 0, stream>>>(qh, ql, kh, kl, vh, vl, cq, Scx);

    w_quant_k<<<wn / 1024, 256, 0, stream>>>(wo, wdq, wn);
    gemm_k<1><<<gg, 256, 0, stream>>>(cq, Scx, wdq, so, nullptr, nullptr, (float*)d_out, Mr, Cdim, Cdim);
}